// Round 11
// baseline (462.352 us; speedup 1.0000x reference)
//
#include <hip/hip_runtime.h>
#include <hip/hip_bf16.h>
#include <math.h>

#define IN_CH   128
#define HC      256   // HEADS*OUT_C
#define OUT_C   64

typedef unsigned short ushort_t;
typedef __attribute__((ext_vector_type(2))) float v2f;
typedef __attribute__((ext_vector_type(4))) float v4f;

__device__ __forceinline__ ushort_t f2bf_rne(float f) {
    unsigned u = __float_as_uint(f);
    unsigned r = (u + 0x7FFFu + ((u >> 16) & 1u)) >> 16;
    return (ushort_t)r;
}
__device__ __forceinline__ v2f bfpair(unsigned u) {
    v2f r;
    r.x = __uint_as_float(u << 16);
    r.y = __uint_as_float(u & 0xffff0000u);
    return r;
}
__device__ __forceinline__ v2f vmax0(v2f a) {
    v2f r;
    r.x = fmaxf(a.x, 0.f);
    r.y = fmaxf(a.y, 0.f);
    return r;
}

// ---- nontemporal (no-allocate) access helpers: keep streams out of L2/L3 ----
__device__ __forceinline__ float4 ntld4(const float* p) {
    v4f t = __builtin_nontemporal_load((const v4f*)p);
    return make_float4(t.x, t.y, t.z, t.w);
}
__device__ __forceinline__ int ntldi(const int* p) {
    return __builtin_nontemporal_load(p);
}
__device__ __forceinline__ void ntst4(float* p, float4 v) {
    v4f t = {v.x, v.y, v.z, v.w};
    __builtin_nontemporal_store(t, (v4f*)p);
}
__device__ __forceinline__ void ntsti(int* p, int v) {
    __builtin_nontemporal_store(v, p);
}

// ===========================================================================
// GEMM tile: 32 rows x 256 cols = x @ W; bf16 out cached (gather table),
// f32 out nontemporal (streaming).
// ===========================================================================
__device__ __forceinline__ void dev_gemm(const float* __restrict__ x,
                                         const float* __restrict__ W,
                                         float* __restrict__ outf,
                                         ushort_t* __restrict__ outh,
                                         int n, int bx, float* xs) {
    const int tid  = threadIdx.x;
    const int row0 = bx * 32;
    {
        const float4* x4 = (const float4*)x;
        const int maxg = n * (IN_CH / 4) - 1;
        float4* xs4 = (float4*)xs;
#pragma unroll
        for (int i = 0; i < 4; ++i) {
            int g = row0 * (IN_CH / 4) + i * 256 + tid;
            xs4[i * 256 + tid] = x4[g > maxg ? maxg : g];
        }
    }
    __syncthreads();
    const int c4 = tid & 63;
    const int rg = tid >> 6;
    const float4* Wv = (const float4*)W;
    v2f acc[8][2];
#pragma unroll
    for (int j = 0; j < 8; ++j) {
        acc[j][0] = (v2f){0.f, 0.f};
        acc[j][1] = (v2f){0.f, 0.f};
    }

    for (int k = 0; k < IN_CH; k += 4) {
        const float4 w0 = Wv[(k + 0) * 64 + c4];
        const float4 w1 = Wv[(k + 1) * 64 + c4];
        const float4 w2 = Wv[(k + 2) * 64 + c4];
        const float4 w3 = Wv[(k + 3) * 64 + c4];
        const v2f w0a = {w0.x, w0.y}, w0b = {w0.z, w0.w};
        const v2f w1a = {w1.x, w1.y}, w1b = {w1.z, w1.w};
        const v2f w2a = {w2.x, w2.y}, w2b = {w2.z, w2.w};
        const v2f w3a = {w3.x, w3.y}, w3b = {w3.z, w3.w};
#pragma unroll
        for (int j = 0; j < 8; ++j) {
            const float4 xv = *(const float4*)(xs + (j * 4 + rg) * IN_CH + k);
            const v2f s0 = {xv.x, xv.x}, s1 = {xv.y, xv.y};
            const v2f s2 = {xv.z, xv.z}, s3 = {xv.w, xv.w};
            acc[j][0] = s0 * w0a + acc[j][0];
            acc[j][1] = s0 * w0b + acc[j][1];
            acc[j][0] = s1 * w1a + acc[j][0];
            acc[j][1] = s1 * w1b + acc[j][1];
            acc[j][0] = s2 * w2a + acc[j][0];
            acc[j][1] = s2 * w2b + acc[j][1];
            acc[j][0] = s3 * w3a + acc[j][0];
            acc[j][1] = s3 * w3b + acc[j][1];
        }
    }
#pragma unroll
    for (int j = 0; j < 8; ++j) {
        const int row = row0 + j * 4 + rg;
        if (row < n) {
            if (outh) {
                ushort4 h;
                h.x = f2bf_rne(acc[j][0].x);
                h.y = f2bf_rne(acc[j][0].y);
                h.z = f2bf_rne(acc[j][1].x);
                h.w = f2bf_rne(acc[j][1].y);
                ((ushort4*)(outh + (size_t)row * HC))[c4] = h;   // cached: gather table
            } else {
                ntst4(outf + (size_t)row * HC + 4 * c4,
                      make_float4(acc[j][0].x, acc[j][0].y, acc[j][1].x, acc[j][1].y));
            }
        }
    }
}

// Atomic-free scatter; csr stores BYTE offsets (src*512). All traffic NT.
__device__ __forceinline__ void dev_scatter_rank(const int* __restrict__ src1,
                                                 const int* __restrict__ dst1, int E1,
                                                 const int* __restrict__ src2,
                                                 const int* __restrict__ dst2, int E2,
                                                 int n, const int* __restrict__ offs,
                                                 const int* __restrict__ rank,
                                                 int* __restrict__ csr,
                                                 int bid, int nB) {
    const int Et = E1 + E2;
    for (int i = bid * 256 + threadIdx.x; i < Et; i += nB * 256) {
        if (i < E1) {
            ntsti(&csr[offs[ntldi(dst1 + i)] + ntldi(rank + i)], ntldi(src1 + i) << 9);
        } else {
            int j = i - E1;
            ntsti(&csr[offs[n + ntldi(dst2 + j)] + ntldi(rank + i)], ntldi(src2 + j) << 9);
        }
    }
}

// ===========================================================================
// BOTH-HOP fused aggregation; gathers cached, everything else nontemporal.
// ===========================================================================
__global__ __launch_bounds__(256) void k_aggboth(const ushort_t* __restrict__ xlh,
                                                 const float* __restrict__ xr0,
                                                 const float* __restrict__ xr1,
                                                 const float* __restrict__ att0,
                                                 const float* __restrict__ att1,
                                                 const int* __restrict__ offs,
                                                 const int* __restrict__ deg,
                                                 const int* __restrict__ csr,
                                                 int n, float* __restrict__ out,
                                                 const float* __restrict__ theta) {
    const int lane = threadIdx.x & 63;
    int node_ = blockIdx.x * 4 + (threadIdx.x >> 6);
    if (node_ >= n) return;
    const int node = __builtin_amdgcn_readfirstlane(node_);

    const float4 at0 = ((const float4*)att0)[lane];
    const float4 at1 = ((const float4*)att1)[lane];
    const v2f a2_0a = {0.2f * at0.x, 0.2f * at0.y}, a2_0b = {0.2f * at0.z, 0.2f * at0.w};
    const v2f a8_0a = {0.8f * at0.x, 0.8f * at0.y}, a8_0b = {0.8f * at0.z, 0.8f * at0.w};
    const v2f a2_1a = {0.2f * at1.x, 0.2f * at1.y}, a2_1b = {0.2f * at1.z, 0.2f * at1.w};
    const v2f a8_1a = {0.8f * at1.x, 0.8f * at1.y}, a8_1b = {0.8f * at1.z, 0.8f * at1.w};
    const float4 q0 = ntld4(xr0 + (size_t)node * HC + 4 * lane);
    const float4 q1 = ntld4(xr1 + (size_t)node * HC + 4 * lane);
    const v2f x0a = {q0.x, q0.y}, x0b = {q0.z, q0.w};
    const v2f x1a = {q1.x, q1.y}, x1b = {q1.z, q1.w};

    const int t0 = deg[node];
    const int s0 = offs[node];
    const int t1 = deg[n + node];
    const int s1 = offs[n + node];

    const char* Xc = (const char*)xlh;
    const unsigned laneB = (unsigned)lane * 8u;
    auto gat = [&](int off) -> uint2 {            // cached: the hot table
        return *(const uint2*)(Xc + (unsigned)off + laneB);
    };

    float l0 = 0.f, l1 = 0.f;
    v2f O0a = {0.f, 0.f}, O0b = {0.f, 0.f};
    v2f O1a = {0.f, 0.f}, O1b = {0.f, 0.f};

    auto proc = [&](uint2 w, const v2f& xa, const v2f& xb,
                    const v2f& a8a, const v2f& a8b,
                    const v2f& a2a, const v2f& a2b, float& l, v2f& Oa, v2f& Ob) {
        v2f ca = bfpair(w.x), cb = bfpair(w.y);
        v2f za = ca + xa, zb = cb + xb;
        v2f t = a2a * za + a2b * zb + a8a * vmax0(za) + a8b * vmax0(zb);
        float part = t.x + t.y;
        part += __shfl_xor(part, 1);
        part += __shfl_xor(part, 2);
        part += __shfl_xor(part, 4);
        part += __shfl_xor(part, 8);
        float p = __expf(fminf(part, 60.f));
        l += p;
        v2f pp = {p, p};
        Oa = pp * ca + Oa;
        Ob = pp * cb + Ob;
    };
    auto proc0 = [&](uint2 w) { proc(w, x0a, x0b, a8_0a, a8_0b, a2_0a, a2_0b, l0, O0a, O0b); };
    auto proc1 = [&](uint2 w) { proc(w, x1a, x1b, a8_1a, a8_1b, a2_1a, a2_1b, l1, O1a, O1b); };

    proc0(gat(node << 9));               // virtual self loop

    const int t0m1 = t0 - 1, t1m1 = t1 - 1;
    auto ld0 = [&](int i) -> uint2 { return gat(ntldi(csr + s0 + i)); };
    auto ld1 = [&](int i) -> uint2 { return gat(ntldi(csr + s1 + i)); };

    uint2 a0 = {0, 0}, a1 = a0, a2 = a0, a3 = a0;
    uint2 b0 = a0, b1 = a0, b2 = a0, b3 = a0;
    if (t0 > 0) {
        a0 = ld0(0);
        a1 = ld0(min(1, t0m1));
        a2 = ld0(min(2, t0m1));
        a3 = ld0(min(3, t0m1));
    }
    if (t1 > 0) {
        b0 = ld1(0);
        b1 = ld1(min(1, t1m1));
        b2 = ld1(min(2, t1m1));
        b3 = ld1(min(3, t1m1));
    }

    const int k = t0 < t1 ? t0 : t1;
    int i = 0;
    for (; i + 2 <= k; i += 2) {
        uint2 c0 = a0, c1 = a1, d0 = b0, d1 = b1;
        a0 = a2; a1 = a3;
        b0 = b2; b1 = b3;
        a2 = ld0(min(i + 4, t0m1));
        b2 = ld1(min(i + 4, t1m1));
        a3 = ld0(min(i + 5, t0m1));
        b3 = ld1(min(i + 5, t1m1));
        proc0(c0);
        proc1(d0);
        proc0(c1);
        proc1(d1);
    }
    for (int i0 = i; i0 < t0; ++i0) {
        uint2 c = a0;
        a0 = a1; a1 = a2; a2 = a3;
        a3 = ld0(min(i0 + 4, t0m1));
        proc0(c);
    }
    for (int i1 = i; i1 < t1; ++i1) {
        uint2 c = b0;
        b0 = b1; b1 = b2; b2 = b3;
        b3 = ld1(min(i1 + 4, t1m1));
        proc1(c);
    }

    const float inv0 = 0.25f / l0;
    const float inv1 = (l1 > 0.f) ? 0.25f / l1 : 0.f;
    const float sg = 1.f / (1.f + __expf(-theta[0]));
    float vx = O0a.x * inv0 + sg * (O1a.x * inv1);
    float vy = O0a.y * inv0 + sg * (O1a.y * inv1);
    float vz = O0b.x * inv0 + sg * (O1b.x * inv1);
    float vw = O0b.y * inv0 + sg * (O1b.y * inv1);
    vx += __shfl_xor(vx, 16); vx += __shfl_xor(vx, 32);
    vy += __shfl_xor(vy, 16); vy += __shfl_xor(vy, 32);
    vz += __shfl_xor(vz, 16); vz += __shfl_xor(vz, 32);
    vw += __shfl_xor(vw, 16); vw += __shfl_xor(vw, 32);

    if (lane < 16) {
        ntst4(out + (size_t)node * OUT_C + 4 * lane, make_float4(vx, vy, vz, vw));
    }
}

// ===========================================================================
// Single-hop aggregation (fallback path).
// ===========================================================================
__device__ __forceinline__ void dev_agg(const ushort_t* __restrict__ xlh,
                                        const float* __restrict__ xr,
                                        const float* __restrict__ att,
                                        const int* __restrict__ offs,
                                        const int* __restrict__ deg,
                                        const int* __restrict__ csr_src,
                                        int n, float* __restrict__ out,
                                        int selfLoop,
                                        const float* __restrict__ theta,
                                        int accumulate, int bid) {
    const int lane = threadIdx.x & 63;
    const int node = bid * 4 + (threadIdx.x >> 6);
    if (node >= n) return;

    const float4 attv = ((const float4*)att)[lane];
    const v2f a2a = {0.2f * attv.x, 0.2f * attv.y}, a2b = {0.2f * attv.z, 0.2f * attv.w};
    const v2f a8a = {0.8f * attv.x, 0.8f * attv.y}, a8b = {0.8f * attv.z, 0.8f * attv.w};
    const float4 q = ntld4(xr + (size_t)node * HC + 4 * lane);
    const v2f xa = {q.x, q.y}, xb = {q.z, q.w};
    const int start2 = offs[node] - selfLoop;
    const int total  = deg[node] + selfLoop;
    const int tm1 = total - 1;

    float l = 0.f;
    v2f Oa = {0.f, 0.f}, Ob = {0.f, 0.f};
    const char* Xc = (const char*)xlh;
    const unsigned laneB = (unsigned)lane * 8u;

    auto ld = [&](int i) -> uint2 {
        int off = (selfLoop && i == 0) ? (node << 9) : ntldi(csr_src + start2 + i);
        return *(const uint2*)(Xc + (unsigned)off + laneB);
    };
    auto process = [&](uint2 w) {
        v2f ca = bfpair(w.x), cb = bfpair(w.y);
        v2f za = ca + xa, zb = cb + xb;
        v2f t = a2a * za + a2b * zb + a8a * vmax0(za) + a8b * vmax0(zb);
        float part = t.x + t.y;
        part += __shfl_xor(part, 1);
        part += __shfl_xor(part, 2);
        part += __shfl_xor(part, 4);
        part += __shfl_xor(part, 8);
        float p = __expf(fminf(part, 60.f));
        l += p;
        v2f pp = {p, p};
        Oa = pp * ca + Oa;
        Ob = pp * cb + Ob;
    };

    if (total > 0) {
        uint2 b0 = ld(0);
        uint2 b1 = ld(min(1, tm1));
        uint2 b2 = ld(min(2, tm1));
        uint2 b3 = ld(min(3, tm1));
        int i = 0;
        for (; i + 4 <= total; i += 4) {
            uint2 c0 = b0, c1 = b1, c2 = b2, c3 = b3;
            b0 = ld(min(i + 4, tm1));
            b1 = ld(min(i + 5, tm1));
            b2 = ld(min(i + 6, tm1));
            b3 = ld(min(i + 7, tm1));
            process(c0);
            process(c1);
            process(c2);
            process(c3);
        }
        const int rem = total - i;
        if (rem > 0) process(b0);
        if (rem > 1) process(b1);
        if (rem > 2) process(b2);
    }

    float inv = (l > 0.f) ? 0.25f / l : 0.f;
    float vx = Oa.x * inv, vy = Oa.y * inv, vz = Ob.x * inv, vw = Ob.y * inv;
    vx += __shfl_xor(vx, 16); vx += __shfl_xor(vx, 32);
    vy += __shfl_xor(vy, 16); vy += __shfl_xor(vy, 32);
    vz += __shfl_xor(vz, 16); vz += __shfl_xor(vz, 32);
    vw += __shfl_xor(vw, 16); vw += __shfl_xor(vw, 32);

    if (lane < 16) {
        float4 r = make_float4(vx, vy, vz, vw);
        float4* op = (float4*)(out + (size_t)node * OUT_C);
        if (accumulate) {
            float sg = 1.f / (1.f + __expf(-theta[0]));
            float4 cur = op[lane];
            r.x = fmaf(sg, r.x, cur.x);
            r.y = fmaf(sg, r.y, cur.y);
            r.z = fmaf(sg, r.z, cur.z);
            r.w = fmaf(sg, r.w, cur.w);
        }
        op[lane] = r;
    }
}

// ===========================================================================
// Mixed-grid kernels
// ===========================================================================

// mix1: [0,GH) hist+rank both hops | [GH,GH+gG) gemm Wl->bf16 | gemm Wr0->f32
__global__ __launch_bounds__(256) void k_mix1(const float* __restrict__ x,
                                              const float* __restrict__ Wa,
                                              ushort_t* __restrict__ oah,
                                              const float* __restrict__ Wb,
                                              float* __restrict__ ob, int n,
                                              int GH, int gG,
                                              const int* __restrict__ dst1, int E1,
                                              const int* __restrict__ dst2, int E2,
                                              int* __restrict__ deg,
                                              int* __restrict__ rank) {
    __shared__ float xs[32 * IN_CH];
    const int bx = blockIdx.x;
    if (bx < GH) {
        const int Et = E1 + E2;
        for (int i = bx * 256 + threadIdx.x; i < Et; i += GH * 256) {
            if (i < E1) ntsti(rank + i, atomicAdd(&deg[ntldi(dst1 + i)], 1));
            else        ntsti(rank + i, atomicAdd(&deg[n + ntldi(dst2 + i - E1)], 1));
        }
    } else {
        int t = bx - GH;
        if (t < gG) dev_gemm(x, Wa, nullptr, oah, n, t, xs);
        else        dev_gemm(x, Wb, ob, nullptr, n, t - gG, xs);
    }
}

// mix2: [0,GS) rank-scatter both hops | [GS,GS+gG) gemm Wc->f32
__global__ __launch_bounds__(256) void k_mix2(const float* __restrict__ x,
                                              const float* __restrict__ Wc,
                                              float* __restrict__ oc, int n,
                                              int GS,
                                              const int* __restrict__ src1,
                                              const int* __restrict__ dst1, int E1,
                                              const int* __restrict__ src2,
                                              const int* __restrict__ dst2, int E2,
                                              const int* __restrict__ offs,
                                              const int* __restrict__ rank,
                                              int* __restrict__ csr) {
    __shared__ float xs[32 * IN_CH];
    const int bx = blockIdx.x;
    if (bx < GS)
        dev_scatter_rank(src1, dst1, E1, src2, dst2, E2, n, offs, rank, csr, bx, GS);
    else
        dev_gemm(x, Wc, oc, nullptr, n, bx - GS, xs);
}

// mix3 (fallback): single-hop agg
__global__ __launch_bounds__(256) void k_mix3(const ushort_t* __restrict__ xlh,
                                              const float* __restrict__ xr,
                                              const float* __restrict__ att,
                                              const int* __restrict__ offs,
                                              const int* __restrict__ deg,
                                              const int* __restrict__ csr_src,
                                              int n, float* __restrict__ out,
                                              int selfLoop,
                                              const float* __restrict__ theta,
                                              int accumulate) {
    dev_agg(xlh, xr, att, offs, deg, csr_src, n, out, selfLoop, theta,
            accumulate, blockIdx.x);
}

// ===========================================================================
// Scan chain
// ===========================================================================
__global__ void k_zero(int* p, int n) {
    int i = blockIdx.x * 256 + threadIdx.x;
    if (i < n) p[i] = 0;
}

__global__ __launch_bounds__(1024) void k_scanA(const int* __restrict__ deg, int n,
                                                int* __restrict__ incl,
                                                int* __restrict__ bsum) {
    __shared__ int sm[1024];
    const int t = threadIdx.x;
    const int i = blockIdx.x * 1024 + t;
    sm[t] = (i < n) ? deg[i] : 0;
    for (int off = 1; off < 1024; off <<= 1) {
        __syncthreads();
        int u = (t >= off) ? sm[t - off] : 0;
        __syncthreads();
        sm[t] += u;
    }
    if (i < n) incl[i] = sm[t];
    if (t == 1023) bsum[blockIdx.x] = sm[1023];
}

__global__ __launch_bounds__(1024) void k_scanB(int* __restrict__ bsum, int nb) {
    __shared__ int sm[1024];
    const int t = threadIdx.x;
    sm[t] = (t < nb) ? bsum[t] : 0;
    for (int off = 1; off < 1024; off <<= 1) {
        __syncthreads();
        int u = (t >= off) ? sm[t - off] : 0;
        __syncthreads();
        sm[t] += u;
    }
    if (t < nb) bsum[t] = sm[t];
}

// scanC with fused bsum prefix (nb <= 128).
__global__ void k_scanCf(const int* __restrict__ incl, const int* __restrict__ deg,
                         const int* __restrict__ bsum, int nb, int n,
                         int* __restrict__ offs) {
    __shared__ int sb[128];
    const int t = threadIdx.x;
    if (t < 128) sb[t] = (t < nb) ? bsum[t] : 0;
    __syncthreads();
#pragma unroll
    for (int off = 1; off < 128; off <<= 1) {
        int u = (t >= off && t < 128) ? sb[t - off] : 0;
        __syncthreads();
        if (t < 128) sb[t] += u;
        __syncthreads();
    }
    int i = blockIdx.x * 256 + t;
    if (i < n) {
        int b    = i >> 10;
        int base = (b > 0) ? sb[b - 1] : 0;
        offs[i] = base + incl[i] - deg[i];
    }
}

__global__ void k_scanC(const int* __restrict__ incl, const int* __restrict__ deg,
                        const int* __restrict__ bsum, int n,
                        int* __restrict__ offs) {
    int i = blockIdx.x * 256 + threadIdx.x;
    if (i < n) {
        int b    = i >> 10;
        int base = (b > 0) ? bsum[b - 1] : 0;
        offs[i] = base + incl[i] - deg[i];
    }
}

// ---------------------------------------------------------------------------
extern "C" void kernel_launch(void* const* d_in, const int* in_sizes, int n_in,
                              void* d_out, int out_size, void* d_ws, size_t ws_size,
                              hipStream_t stream) {
    const float* x     = (const float*)d_in[0];
    const int*   e1    = (const int*)d_in[1];
    const int*   e2    = (const int*)d_in[2];
    const float* Wl    = (const float*)d_in[3];
    const float* Wr0   = (const float*)d_in[4];
    const float* Wr1   = (const float*)d_in[5];
    const float* att0  = (const float*)d_in[6];
    const float* att1  = (const float*)d_in[7];
    const float* theta = (const float*)d_in[8];

    const int n  = in_sizes[0] / IN_CH;  // 50000
    const int E1 = in_sizes[1] / 2;
    const int E2 = in_sizes[2] / 2;
    float* out = (float*)d_out;

    char* w = (char*)d_ws;
    auto alloc = [&](size_t bytes) -> char* {
        char* p = w;
        w += (bytes + 255) & ~(size_t)255;
        return p;
    };
    const size_t projH = (size_t)n * HC * 2;   // bf16 xl
    const size_t projF = (size_t)n * HC * 4;   // f32 xr
    const size_t eB    = (size_t)(E1 + E2) * 4;
    const size_t need3 = ((projH + 255) & ~(size_t)255)
                       + 2 * ((projF + 255) & ~(size_t)255)
                       + 2 * ((eB + 255) & ~(size_t)255)
                       + 3 * (((size_t)2 * n * 4 + 255) & ~(size_t)255) + 4096;
    const bool threeBuf = ws_size >= need3;

    ushort_t* xlh = (ushort_t*)alloc(projH);
    float* xr0 = (float*)alloc(projF);
    float* xr1 = threeBuf ? (float*)alloc(projF) : xr0;
    int* csr  = (int*)alloc(eB);
    int* rank = (int*)alloc(eB);
    int* deg  = (int*)alloc((size_t)2 * n * 4);
    int* offs = (int*)alloc((size_t)2 * n * 4);
    int* tmp  = (int*)alloc((size_t)2 * n * 4);   // incl scratch
    int* bsum = (int*)alloc(4096);

    const int gG    = (n + 31) / 32;
    const int GA    = (n + 3) / 4;
    const int GH    = 2048;
    const int GS    = 2048;
    const int n2    = 2 * n;
    const int gN2   = (n2 + 255) / 256;
    const int nScan = (n2 + 1023) / 1024;

    k_zero<<<gN2, 256, 0, stream>>>(deg, n2);
    // hist+rank (both hops) || gemm Wl (bf16) || gemm Wr0 (f32)
    k_mix1<<<GH + 2 * gG, 256, 0, stream>>>(x, Wl, xlh, Wr0, xr0, n, GH, gG,
                                            e1 + E1, E1, e2 + E2, E2, deg, rank);
    k_scanA<<<nScan, 1024, 0, stream>>>(deg, n2, tmp, bsum);
    if (nScan <= 128) {
        k_scanCf<<<gN2, 256, 0, stream>>>(tmp, deg, bsum, nScan, n2, offs);
    } else {
        k_scanB<<<1, 1024, 0, stream>>>(bsum, nScan);
        k_scanC<<<gN2, 256, 0, stream>>>(tmp, deg, bsum, n2, offs);
    }

    if (threeBuf) {
        // atomic-free scatter both hops || gemm Wr1
        k_mix2<<<GS + gG, 256, 0, stream>>>(x, Wr1, xr1, n, GS,
                                            e1, e1 + E1, E1, e2, e2 + E2, E2,
                                            offs, rank, csr);
        // fused both-hop aggregation
        k_aggboth<<<GA, 256, 0, stream>>>(xlh, xr0, xr1, att0, att1,
                                          offs, deg, csr, n, out, theta);
    } else {
        // fallback (xr1 aliases xr0): scatter alone, serial aggs
        k_mix2<<<GS, 256, 0, stream>>>(x, Wr1, xr1, n, GS,
                                       e1, e1 + E1, E1, e2, e2 + E2, E2,
                                       offs, rank, csr);
        k_mix3<<<GA, 256, 0, stream>>>(xlh, xr0, att0, offs, deg, csr, n, out,
                                       1, theta, 0);
        k_mix2<<<gG, 256, 0, stream>>>(x, Wr1, xr0, n, 0,
                                       (const int*)nullptr, (const int*)nullptr, 0,
                                       (const int*)nullptr, (const int*)nullptr, 0,
                                       (const int*)nullptr, (const int*)nullptr,
                                       (int*)nullptr);
        k_mix3<<<GA, 256, 0, stream>>>(xlh, xr0, att1, offs + n, deg + n, csr, n, out,
                                       0, theta, 1);
    }
}

// Round 12
// 450.241 us; speedup vs baseline: 1.0269x; 1.0269x over previous
//
#include <hip/hip_runtime.h>
#include <hip/hip_bf16.h>
#include <math.h>

#define IN_CH   128
#define HC      256   // HEADS*OUT_C
#define OUT_C   64

typedef unsigned short ushort_t;
typedef __attribute__((ext_vector_type(2))) float v2f;
typedef __attribute__((ext_vector_type(4))) float v4f;

__device__ __forceinline__ ushort_t f2bf_rne(float f) {
    unsigned u = __float_as_uint(f);
    unsigned r = (u + 0x7FFFu + ((u >> 16) & 1u)) >> 16;
    return (ushort_t)r;
}
__device__ __forceinline__ v2f bfpair(unsigned u) {
    v2f r;
    r.x = __uint_as_float(u << 16);
    r.y = __uint_as_float(u & 0xffff0000u);
    return r;
}
__device__ __forceinline__ v2f vmax0(v2f a) {
    v2f r;
    r.x = fmaxf(a.x, 0.f);
    r.y = fmaxf(a.y, 0.f);
    return r;
}

// ---- nontemporal helpers (read/write-once streams) ----
__device__ __forceinline__ float4 ntld4(const float* p) {
    v4f t = __builtin_nontemporal_load((const v4f*)p);
    return make_float4(t.x, t.y, t.z, t.w);
}
__device__ __forceinline__ int ntldi(const int* p) {
    return __builtin_nontemporal_load(p);
}
__device__ __forceinline__ void ntst4(float* p, float4 v) {
    v4f t = {v.x, v.y, v.z, v.w};
    __builtin_nontemporal_store(t, (v4f*)p);
}
__device__ __forceinline__ void ntsti(int* p, int v) {
    __builtin_nontemporal_store(v, p);
}

// ---- 16-lane (DPP-row) sum via row_ror rotations: pure VALU, no LDS pipe.
// Head groups are lanes [0..15],[16..31],[32..47],[48..63] == DPP rows.
#define DPP_ROR_ADD(x, N)                                                   \
    (x) += __uint_as_float(__builtin_amdgcn_update_dpp(                     \
        0, __float_as_uint(x), 0x120 + (N), 0xF, 0xF, true))

__device__ __forceinline__ float rowsum16(float x) {
    DPP_ROR_ADD(x, 8);
    DPP_ROR_ADD(x, 4);
    DPP_ROR_ADD(x, 2);
    DPP_ROR_ADD(x, 1);
    return x;
}

// ===========================================================================
// GEMM tile: 32 rows x 256 cols = x @ W; bf16 out cached (gather table),
// f32 out nontemporal (streaming).
// ===========================================================================
__device__ __forceinline__ void dev_gemm(const float* __restrict__ x,
                                         const float* __restrict__ W,
                                         float* __restrict__ outf,
                                         ushort_t* __restrict__ outh,
                                         int n, int bx, float* xs) {
    const int tid  = threadIdx.x;
    const int row0 = bx * 32;
    {
        const float4* x4 = (const float4*)x;
        const int maxg = n * (IN_CH / 4) - 1;
        float4* xs4 = (float4*)xs;
#pragma unroll
        for (int i = 0; i < 4; ++i) {
            int g = row0 * (IN_CH / 4) + i * 256 + tid;
            xs4[i * 256 + tid] = x4[g > maxg ? maxg : g];
        }
    }
    __syncthreads();
    const int c4 = tid & 63;
    const int rg = tid >> 6;
    const float4* Wv = (const float4*)W;
    v2f acc[8][2];
#pragma unroll
    for (int j = 0; j < 8; ++j) {
        acc[j][0] = (v2f){0.f, 0.f};
        acc[j][1] = (v2f){0.f, 0.f};
    }

    for (int k = 0; k < IN_CH; k += 4) {
        const float4 w0 = Wv[(k + 0) * 64 + c4];
        const float4 w1 = Wv[(k + 1) * 64 + c4];
        const float4 w2 = Wv[(k + 2) * 64 + c4];
        const float4 w3 = Wv[(k + 3) * 64 + c4];
        const v2f w0a = {w0.x, w0.y}, w0b = {w0.z, w0.w};
        const v2f w1a = {w1.x, w1.y}, w1b = {w1.z, w1.w};
        const v2f w2a = {w2.x, w2.y}, w2b = {w2.z, w2.w};
        const v2f w3a = {w3.x, w3.y}, w3b = {w3.z, w3.w};
#pragma unroll
        for (int j = 0; j < 8; ++j) {
            const float4 xv = *(const float4*)(xs + (j * 4 + rg) * IN_CH + k);
            const v2f s0 = {xv.x, xv.x}, s1 = {xv.y, xv.y};
            const v2f s2 = {xv.z, xv.z}, s3 = {xv.w, xv.w};
            acc[j][0] = s0 * w0a + acc[j][0];
            acc[j][1] = s0 * w0b + acc[j][1];
            acc[j][0] = s1 * w1a + acc[j][0];
            acc[j][1] = s1 * w1b + acc[j][1];
            acc[j][0] = s2 * w2a + acc[j][0];
            acc[j][1] = s2 * w2b + acc[j][1];
            acc[j][0] = s3 * w3a + acc[j][0];
            acc[j][1] = s3 * w3b + acc[j][1];
        }
    }
#pragma unroll
    for (int j = 0; j < 8; ++j) {
        const int row = row0 + j * 4 + rg;
        if (row < n) {
            if (outh) {
                ushort4 h;
                h.x = f2bf_rne(acc[j][0].x);
                h.y = f2bf_rne(acc[j][0].y);
                h.z = f2bf_rne(acc[j][1].x);
                h.w = f2bf_rne(acc[j][1].y);
                ((ushort4*)(outh + (size_t)row * HC))[c4] = h;   // cached: gather table
            } else {
                ntst4(outf + (size_t)row * HC + 4 * c4,
                      make_float4(acc[j][0].x, acc[j][0].y, acc[j][1].x, acc[j][1].y));
            }
        }
    }
}

// Atomic-free scatter; csr stores BYTE offsets (src*512). Loads NT,
// csr stores CACHED (random 4B scatter coalesces in L2; NT would write-around).
__device__ __forceinline__ void dev_scatter_rank(const int* __restrict__ src1,
                                                 const int* __restrict__ dst1, int E1,
                                                 const int* __restrict__ src2,
                                                 const int* __restrict__ dst2, int E2,
                                                 int n, const int* __restrict__ offs,
                                                 const int* __restrict__ rank,
                                                 int* __restrict__ csr,
                                                 int bid, int nB) {
    const int Et = E1 + E2;
    for (int i = bid * 256 + threadIdx.x; i < Et; i += nB * 256) {
        if (i < E1) {
            csr[offs[ntldi(dst1 + i)] + ntldi(rank + i)] = ntldi(src1 + i) << 9;
        } else {
            int j = i - E1;
            csr[offs[n + ntldi(dst2 + j)] + ntldi(rank + i)] = ntldi(src2 + j) << 9;
        }
    }
}

// ===========================================================================
// BOTH-HOP fused aggregation; DPP row-sum score reduction (no LDS pipe).
// ===========================================================================
__global__ __launch_bounds__(256) void k_aggboth(const ushort_t* __restrict__ xlh,
                                                 const float* __restrict__ xr0,
                                                 const float* __restrict__ xr1,
                                                 const float* __restrict__ att0,
                                                 const float* __restrict__ att1,
                                                 const int* __restrict__ offs,
                                                 const int* __restrict__ deg,
                                                 const int* __restrict__ csr,
                                                 int n, float* __restrict__ out,
                                                 const float* __restrict__ theta) {
    const int lane = threadIdx.x & 63;
    int node_ = blockIdx.x * 4 + (threadIdx.x >> 6);
    if (node_ >= n) return;
    const int node = __builtin_amdgcn_readfirstlane(node_);

    const float4 at0 = ((const float4*)att0)[lane];
    const float4 at1 = ((const float4*)att1)[lane];
    const v2f a2_0a = {0.2f * at0.x, 0.2f * at0.y}, a2_0b = {0.2f * at0.z, 0.2f * at0.w};
    const v2f a8_0a = {0.8f * at0.x, 0.8f * at0.y}, a8_0b = {0.8f * at0.z, 0.8f * at0.w};
    const v2f a2_1a = {0.2f * at1.x, 0.2f * at1.y}, a2_1b = {0.2f * at1.z, 0.2f * at1.w};
    const v2f a8_1a = {0.8f * at1.x, 0.8f * at1.y}, a8_1b = {0.8f * at1.z, 0.8f * at1.w};
    const float4 q0 = ntld4(xr0 + (size_t)node * HC + 4 * lane);
    const float4 q1 = ntld4(xr1 + (size_t)node * HC + 4 * lane);
    const v2f x0a = {q0.x, q0.y}, x0b = {q0.z, q0.w};
    const v2f x1a = {q1.x, q1.y}, x1b = {q1.z, q1.w};

    const int t0 = deg[node];
    const int s0 = offs[node];
    const int t1 = deg[n + node];
    const int s1 = offs[n + node];

    const char* Xc = (const char*)xlh;
    const unsigned laneB = (unsigned)lane * 8u;
    auto gat = [&](int off) -> uint2 {            // cached: the hot table
        return *(const uint2*)(Xc + (unsigned)off + laneB);
    };

    float l0 = 0.f, l1 = 0.f;
    v2f O0a = {0.f, 0.f}, O0b = {0.f, 0.f};
    v2f O1a = {0.f, 0.f}, O1b = {0.f, 0.f};

    auto proc = [&](uint2 w, const v2f& xa, const v2f& xb,
                    const v2f& a8a, const v2f& a8b,
                    const v2f& a2a, const v2f& a2b, float& l, v2f& Oa, v2f& Ob) {
        v2f ca = bfpair(w.x), cb = bfpair(w.y);
        v2f za = ca + xa, zb = cb + xb;
        v2f t = a2a * za + a2b * zb + a8a * vmax0(za) + a8b * vmax0(zb);
        float part = rowsum16(t.x + t.y);        // DPP, head = DPP row
        float p = __expf(fminf(part, 60.f));
        l += p;
        v2f pp = {p, p};
        Oa = pp * ca + Oa;
        Ob = pp * cb + Ob;
    };
    auto proc0 = [&](uint2 w) { proc(w, x0a, x0b, a8_0a, a8_0b, a2_0a, a2_0b, l0, O0a, O0b); };
    auto proc1 = [&](uint2 w) { proc(w, x1a, x1b, a8_1a, a8_1b, a2_1a, a2_1b, l1, O1a, O1b); };

    proc0(gat(node << 9));               // virtual self loop

    const int t0m1 = t0 - 1, t1m1 = t1 - 1;
    auto ld0 = [&](int i) -> uint2 { return gat(ntldi(csr + s0 + i)); };
    auto ld1 = [&](int i) -> uint2 { return gat(ntldi(csr + s1 + i)); };

    uint2 a0 = {0, 0}, a1 = a0, a2 = a0, a3 = a0;
    uint2 b0 = a0, b1 = a0, b2 = a0, b3 = a0;
    if (t0 > 0) {
        a0 = ld0(0);
        a1 = ld0(min(1, t0m1));
        a2 = ld0(min(2, t0m1));
        a3 = ld0(min(3, t0m1));
    }
    if (t1 > 0) {
        b0 = ld1(0);
        b1 = ld1(min(1, t1m1));
        b2 = ld1(min(2, t1m1));
        b3 = ld1(min(3, t1m1));
    }

    const int k = t0 < t1 ? t0 : t1;
    int i = 0;
    for (; i + 2 <= k; i += 2) {
        uint2 c0 = a0, c1 = a1, d0 = b0, d1 = b1;
        a0 = a2; a1 = a3;
        b0 = b2; b1 = b3;
        a2 = ld0(min(i + 4, t0m1));
        b2 = ld1(min(i + 4, t1m1));
        a3 = ld0(min(i + 5, t0m1));
        b3 = ld1(min(i + 5, t1m1));
        proc0(c0);
        proc1(d0);
        proc0(c1);
        proc1(d1);
    }
    for (int i0 = i; i0 < t0; ++i0) {
        uint2 c = a0;
        a0 = a1; a1 = a2; a2 = a3;
        a3 = ld0(min(i0 + 4, t0m1));
        proc0(c);
    }
    for (int i1 = i; i1 < t1; ++i1) {
        uint2 c = b0;
        b0 = b1; b1 = b2; b2 = b3;
        b3 = ld1(min(i1 + 4, t1m1));
        proc1(c);
    }

    const float inv0 = 0.25f / l0;
    const float inv1 = (l1 > 0.f) ? 0.25f / l1 : 0.f;
    const float sg = 1.f / (1.f + __expf(-theta[0]));
    float vx = O0a.x * inv0 + sg * (O1a.x * inv1);
    float vy = O0a.y * inv0 + sg * (O1a.y * inv1);
    float vz = O0b.x * inv0 + sg * (O1b.x * inv1);
    float vw = O0b.y * inv0 + sg * (O1b.y * inv1);
    vx += __shfl_xor(vx, 16); vx += __shfl_xor(vx, 32);
    vy += __shfl_xor(vy, 16); vy += __shfl_xor(vy, 32);
    vz += __shfl_xor(vz, 16); vz += __shfl_xor(vz, 32);
    vw += __shfl_xor(vw, 16); vw += __shfl_xor(vw, 32);

    if (lane < 16) {
        ntst4(out + (size_t)node * OUT_C + 4 * lane, make_float4(vx, vy, vz, vw));
    }
}

// ===========================================================================
// Single-hop aggregation (fallback path).
// ===========================================================================
__device__ __forceinline__ void dev_agg(const ushort_t* __restrict__ xlh,
                                        const float* __restrict__ xr,
                                        const float* __restrict__ att,
                                        const int* __restrict__ offs,
                                        const int* __restrict__ deg,
                                        const int* __restrict__ csr_src,
                                        int n, float* __restrict__ out,
                                        int selfLoop,
                                        const float* __restrict__ theta,
                                        int accumulate, int bid) {
    const int lane = threadIdx.x & 63;
    const int node = bid * 4 + (threadIdx.x >> 6);
    if (node >= n) return;

    const float4 attv = ((const float4*)att)[lane];
    const v2f a2a = {0.2f * attv.x, 0.2f * attv.y}, a2b = {0.2f * attv.z, 0.2f * attv.w};
    const v2f a8a = {0.8f * attv.x, 0.8f * attv.y}, a8b = {0.8f * attv.z, 0.8f * attv.w};
    const float4 q = ntld4(xr + (size_t)node * HC + 4 * lane);
    const v2f xa = {q.x, q.y}, xb = {q.z, q.w};
    const int start2 = offs[node] - selfLoop;
    const int total  = deg[node] + selfLoop;
    const int tm1 = total - 1;

    float l = 0.f;
    v2f Oa = {0.f, 0.f}, Ob = {0.f, 0.f};
    const char* Xc = (const char*)xlh;
    const unsigned laneB = (unsigned)lane * 8u;

    auto ld = [&](int i) -> uint2 {
        int off = (selfLoop && i == 0) ? (node << 9) : ntldi(csr_src + start2 + i);
        return *(const uint2*)(Xc + (unsigned)off + laneB);
    };
    auto process = [&](uint2 w) {
        v2f ca = bfpair(w.x), cb = bfpair(w.y);
        v2f za = ca + xa, zb = cb + xb;
        v2f t = a2a * za + a2b * zb + a8a * vmax0(za) + a8b * vmax0(zb);
        float part = rowsum16(t.x + t.y);
        float p = __expf(fminf(part, 60.f));
        l += p;
        v2f pp = {p, p};
        Oa = pp * ca + Oa;
        Ob = pp * cb + Ob;
    };

    if (total > 0) {
        uint2 b0 = ld(0);
        uint2 b1 = ld(min(1, tm1));
        uint2 b2 = ld(min(2, tm1));
        uint2 b3 = ld(min(3, tm1));
        int i = 0;
        for (; i + 4 <= total; i += 4) {
            uint2 c0 = b0, c1 = b1, c2 = b2, c3 = b3;
            b0 = ld(min(i + 4, tm1));
            b1 = ld(min(i + 5, tm1));
            b2 = ld(min(i + 6, tm1));
            b3 = ld(min(i + 7, tm1));
            process(c0);
            process(c1);
            process(c2);
            process(c3);
        }
        const int rem = total - i;
        if (rem > 0) process(b0);
        if (rem > 1) process(b1);
        if (rem > 2) process(b2);
    }

    float inv = (l > 0.f) ? 0.25f / l : 0.f;
    float vx = Oa.x * inv, vy = Oa.y * inv, vz = Ob.x * inv, vw = Ob.y * inv;
    vx += __shfl_xor(vx, 16); vx += __shfl_xor(vx, 32);
    vy += __shfl_xor(vy, 16); vy += __shfl_xor(vy, 32);
    vz += __shfl_xor(vz, 16); vz += __shfl_xor(vz, 32);
    vw += __shfl_xor(vw, 16); vw += __shfl_xor(vw, 32);

    if (lane < 16) {
        float4 r = make_float4(vx, vy, vz, vw);
        float4* op = (float4*)(out + (size_t)node * OUT_C);
        if (accumulate) {
            float sg = 1.f / (1.f + __expf(-theta[0]));
            float4 cur = op[lane];
            r.x = fmaf(sg, r.x, cur.x);
            r.y = fmaf(sg, r.y, cur.y);
            r.z = fmaf(sg, r.z, cur.z);
            r.w = fmaf(sg, r.w, cur.w);
        }
        op[lane] = r;
    }
}

// ===========================================================================
// Mixed-grid kernels
// ===========================================================================

// mix1: [0,GH) hist+rank both hops | [GH,GH+gG) gemm Wl->bf16 | gemm Wr0->f32
__global__ __launch_bounds__(256) void k_mix1(const float* __restrict__ x,
                                              const float* __restrict__ Wa,
                                              ushort_t* __restrict__ oah,
                                              const float* __restrict__ Wb,
                                              float* __restrict__ ob, int n,
                                              int GH, int gG,
                                              const int* __restrict__ dst1, int E1,
                                              const int* __restrict__ dst2, int E2,
                                              int* __restrict__ deg,
                                              int* __restrict__ rank) {
    __shared__ float xs[32 * IN_CH];
    const int bx = blockIdx.x;
    if (bx < GH) {
        const int Et = E1 + E2;
        for (int i = bx * 256 + threadIdx.x; i < Et; i += GH * 256) {
            if (i < E1) ntsti(rank + i, atomicAdd(&deg[ntldi(dst1 + i)], 1));
            else        ntsti(rank + i, atomicAdd(&deg[n + ntldi(dst2 + i - E1)], 1));
        }
    } else {
        int t = bx - GH;
        if (t < gG) dev_gemm(x, Wa, nullptr, oah, n, t, xs);
        else        dev_gemm(x, Wb, ob, nullptr, n, t - gG, xs);
    }
}

// mix2: [0,GS) rank-scatter both hops | [GS,GS+gG) gemm Wc->f32
__global__ __launch_bounds__(256) void k_mix2(const float* __restrict__ x,
                                              const float* __restrict__ Wc,
                                              float* __restrict__ oc, int n,
                                              int GS,
                                              const int* __restrict__ src1,
                                              const int* __restrict__ dst1, int E1,
                                              const int* __restrict__ src2,
                                              const int* __restrict__ dst2, int E2,
                                              const int* __restrict__ offs,
                                              const int* __restrict__ rank,
                                              int* __restrict__ csr) {
    __shared__ float xs[32 * IN_CH];
    const int bx = blockIdx.x;
    if (bx < GS)
        dev_scatter_rank(src1, dst1, E1, src2, dst2, E2, n, offs, rank, csr, bx, GS);
    else
        dev_gemm(x, Wc, oc, nullptr, n, bx - GS, xs);
}

// mix3 (fallback): single-hop agg
__global__ __launch_bounds__(256) void k_mix3(const ushort_t* __restrict__ xlh,
                                              const float* __restrict__ xr,
                                              const float* __restrict__ att,
                                              const int* __restrict__ offs,
                                              const int* __restrict__ deg,
                                              const int* __restrict__ csr_src,
                                              int n, float* __restrict__ out,
                                              int selfLoop,
                                              const float* __restrict__ theta,
                                              int accumulate) {
    dev_agg(xlh, xr, att, offs, deg, csr_src, n, out, selfLoop, theta,
            accumulate, blockIdx.x);
}

// ===========================================================================
// Scan chain
// ===========================================================================
__global__ void k_zero(int* p, int n) {
    int i = blockIdx.x * 256 + threadIdx.x;
    if (i < n) p[i] = 0;
}

__global__ __launch_bounds__(1024) void k_scanA(const int* __restrict__ deg, int n,
                                                int* __restrict__ incl,
                                                int* __restrict__ bsum) {
    __shared__ int sm[1024];
    const int t = threadIdx.x;
    const int i = blockIdx.x * 1024 + t;
    sm[t] = (i < n) ? deg[i] : 0;
    for (int off = 1; off < 1024; off <<= 1) {
        __syncthreads();
        int u = (t >= off) ? sm[t - off] : 0;
        __syncthreads();
        sm[t] += u;
    }
    if (i < n) incl[i] = sm[t];
    if (t == 1023) bsum[blockIdx.x] = sm[1023];
}

__global__ __launch_bounds__(1024) void k_scanB(int* __restrict__ bsum, int nb) {
    __shared__ int sm[1024];
    const int t = threadIdx.x;
    sm[t] = (t < nb) ? bsum[t] : 0;
    for (int off = 1; off < 1024; off <<= 1) {
        __syncthreads();
        int u = (t >= off) ? sm[t - off] : 0;
        __syncthreads();
        sm[t] += u;
    }
    if (t < nb) bsum[t] = sm[t];
}

// scanC with fused bsum prefix (nb <= 128).
__global__ void k_scanCf(const int* __restrict__ incl, const int* __restrict__ deg,
                         const int* __restrict__ bsum, int nb, int n,
                         int* __restrict__ offs) {
    __shared__ int sb[128];
    const int t = threadIdx.x;
    if (t < 128) sb[t] = (t < nb) ? bsum[t] : 0;
    __syncthreads();
#pragma unroll
    for (int off = 1; off < 128; off <<= 1) {
        int u = (t >= off && t < 128) ? sb[t - off] : 0;
        __syncthreads();
        if (t < 128) sb[t] += u;
        __syncthreads();
    }
    int i = blockIdx.x * 256 + t;
    if (i < n) {
        int b    = i >> 10;
        int base = (b > 0) ? sb[b - 1] : 0;
        offs[i] = base + incl[i] - deg[i];
    }
}

__global__ void k_scanC(const int* __restrict__ incl, const int* __restrict__ deg,
                        const int* __restrict__ bsum, int n,
                        int* __restrict__ offs) {
    int i = blockIdx.x * 256 + threadIdx.x;
    if (i < n) {
        int b    = i >> 10;
        int base = (b > 0) ? bsum[b - 1] : 0;
        offs[i] = base + incl[i] - deg[i];
    }
}

// ---------------------------------------------------------------------------
extern "C" void kernel_launch(void* const* d_in, const int* in_sizes, int n_in,
                              void* d_out, int out_size, void* d_ws, size_t ws_size,
                              hipStream_t stream) {
    const float* x     = (const float*)d_in[0];
    const int*   e1    = (const int*)d_in[1];
    const int*   e2    = (const int*)d_in[2];
    const float* Wl    = (const float*)d_in[3];
    const float* Wr0   = (const float*)d_in[4];
    const float* Wr1   = (const float*)d_in[5];
    const float* att0  = (const float*)d_in[6];
    const float* att1  = (const float*)d_in[7];
    const float* theta = (const float*)d_in[8];

    const int n  = in_sizes[0] / IN_CH;  // 50000
    const int E1 = in_sizes[1] / 2;
    const int E2 = in_sizes[2] / 2;
    float* out = (float*)d_out;

    char* w = (char*)d_ws;
    auto alloc = [&](size_t bytes) -> char* {
        char* p = w;
        w += (bytes + 255) & ~(size_t)255;
        return p;
    };
    const size_t projH = (size_t)n * HC * 2;   // bf16 xl
    const size_t projF = (size_t)n * HC * 4;   // f32 xr
    const size_t eB    = (size_t)(E1 + E2) * 4;
    const size_t need3 = ((projH + 255) & ~(size_t)255)
                       + 2 * ((projF + 255) & ~(size_t)255)
                       + 2 * ((eB + 255) & ~(size_t)255)
                       + 3 * (((size_t)2 * n * 4 + 255) & ~(size_t)255) + 4096;
    const bool threeBuf = ws_size >= need3;

    ushort_t* xlh = (ushort_t*)alloc(projH);
    float* xr0 = (float*)alloc(projF);
    float* xr1 = threeBuf ? (float*)alloc(projF) : xr0;
    int* csr  = (int*)alloc(eB);
    int* rank = (int*)alloc(eB);
    int* deg  = (int*)alloc((size_t)2 * n * 4);
    int* offs = (int*)alloc((size_t)2 * n * 4);
    int* tmp  = (int*)alloc((size_t)2 * n * 4);   // incl scratch
    int* bsum = (int*)alloc(4096);

    const int gG    = (n + 31) / 32;
    const int GA    = (n + 3) / 4;
    const int GH    = 2048;
    const int GS    = 2048;
    const int n2    = 2 * n;
    const int gN2   = (n2 + 255) / 256;
    const int nScan = (n2 + 1023) / 1024;

    k_zero<<<gN2, 256, 0, stream>>>(deg, n2);
    // hist+rank (both hops) || gemm Wl (bf16) || gemm Wr0 (f32)
    k_mix1<<<GH + 2 * gG, 256, 0, stream>>>(x, Wl, xlh, Wr0, xr0, n, GH, gG,
                                            e1 + E1, E1, e2 + E2, E2, deg, rank);
    k_scanA<<<nScan, 1024, 0, stream>>>(deg, n2, tmp, bsum);
    if (nScan <= 128) {
        k_scanCf<<<gN2, 256, 0, stream>>>(tmp, deg, bsum, nScan, n2, offs);
    } else {
        k_scanB<<<1, 1024, 0, stream>>>(bsum, nScan);
        k_scanC<<<gN2, 256, 0, stream>>>(tmp, deg, bsum, n2, offs);
    }

    if (threeBuf) {
        // atomic-free scatter both hops || gemm Wr1
        k_mix2<<<GS + gG, 256, 0, stream>>>(x, Wr1, xr1, n, GS,
                                            e1, e1 + E1, E1, e2, e2 + E2, E2,
                                            offs, rank, csr);
        // fused both-hop aggregation
        k_aggboth<<<GA, 256, 0, stream>>>(xlh, xr0, xr1, att0, att1,
                                          offs, deg, csr, n, out, theta);
    } else {
        // fallback (xr1 aliases xr0): scatter alone, serial aggs
        k_mix2<<<GS, 256, 0, stream>>>(x, Wr1, xr1, n, GS,
                                       e1, e1 + E1, E1, e2, e2 + E2, E2,
                                       offs, rank, csr);
        k_mix3<<<GA, 256, 0, stream>>>(xlh, xr0, att0, offs, deg, csr, n, out,
                                       1, theta, 0);
        k_mix2<<<gG, 256, 0, stream>>>(x, Wr1, xr0, n, 0,
                                       (const int*)nullptr, (const int*)nullptr, 0,
                                       (const int*)nullptr, (const int*)nullptr, 0,
                                       (const int*)nullptr, (const int*)nullptr,
                                       (int*)nullptr);
        k_mix3<<<GA, 256, 0, stream>>>(xlh, xr0, att1, offs + n, deg + n, csr, n, out,
                                       0, theta, 1);
    }
}